// Round 2
// baseline (292.775 us; speedup 1.0000x reference)
//
#include <hip/hip_runtime.h>
#include <hip/hip_bf16.h>

// MoE top-1: N=16384 tokens, D=1024, E=8 experts.
// out[n] = expert_w[argmax(router(x[n]))] @ x[n] + expert_b[e]
//
// Pipeline: init counts -> convert W to bf16 -> router (f64 logits, lane-parallel
// over experts x stripes, argmax, per-expert token lists, fused x->bf16) ->
// grouped bf16-MFMA GEMM.

#define NTOK 16384
#define DIM  1024
#define NEXP 8

typedef __bf16 bf16x8 __attribute__((ext_vector_type(8)));
typedef float  f32x4  __attribute__((ext_vector_type(4)));

__device__ __forceinline__ unsigned short f2bf(float f) {
  unsigned int u = __builtin_bit_cast(unsigned int, f);
  u += 0x7FFFu + ((u >> 16) & 1u);   // round-to-nearest-even (finite inputs)
  return (unsigned short)(u >> 16);
}

__global__ __launch_bounds__(64) void k_init(int* counts) {
  if (threadIdx.x < NEXP) counts[threadIdx.x] = 0;
}

// expert_w f32 -> bf16, 8 elements per thread. grid 4096 x 256.
__global__ __launch_bounds__(256) void k_convw(const float* __restrict__ src,
                                               unsigned short* __restrict__ dst) {
  size_t i = ((size_t)blockIdx.x * 256 + threadIdx.x) * 8;
  const float4* p = (const float4*)(src + i);
  float4 a = p[0], b = p[1];
  unsigned int w0 = (unsigned)f2bf(a.x) | ((unsigned)f2bf(a.y) << 16);
  unsigned int w1 = (unsigned)f2bf(a.z) | ((unsigned)f2bf(a.w) << 16);
  unsigned int w2 = (unsigned)f2bf(b.x) | ((unsigned)f2bf(b.y) << 16);
  unsigned int w3 = (unsigned)f2bf(b.z) | ((unsigned)f2bf(b.w) << 16);
  *(uint4*)(dst + i) = make_uint4(w0, w1, w2, w3);
}

// Router: one wave per token. lane = (g<<3)|e : expert e in [0,8), stripe g in [0,8).
// Lane accumulates sum_{d in stripe g} x[n][d]*rw[e][d] in f64 (4 accumulators),
// butterfly-sum over g (xor 8,16,32), then parallel max/argmax over e (xor 1,2,4).
// f64 accumulation => argmax matches exact logits (safer than np's own f32).
// Fused: x -> bf16 (lane (g,e) converts chunk e of stripe g).
__global__ __launch_bounds__(256) void k_router(const float* __restrict__ x,
                                                const float* __restrict__ rw,
                                                const float* __restrict__ rb,
                                                unsigned short* __restrict__ xbf,
                                                int* __restrict__ counts,
                                                int* __restrict__ tok) {
  const int lane = threadIdx.x & 63;
  const int wave = threadIdx.x >> 6;
  const int n = (blockIdx.x << 2) + wave;
  const int e = lane & 7;
  const int g = lane >> 3;

  const float* xrow = x + (size_t)n * DIM + g * 128;
  const float* wrow = rw + (e << 10) + g * 128;
  unsigned short* xdst = xbf + (size_t)n * DIM + g * 128;

  double acc[4] = {0.0, 0.0, 0.0, 0.0};
#pragma unroll
  for (int ck = 0; ck < 8; ++ck) {
    float xv[16], wv[16];
    const float4* xp = (const float4*)(xrow + ck * 16);
    const float4* wp = (const float4*)(wrow + ck * 16);
#pragma unroll
    for (int i = 0; i < 4; ++i) *(float4*)&xv[i * 4] = xp[i];
#pragma unroll
    for (int i = 0; i < 4; ++i) *(float4*)&wv[i * 4] = wp[i];
#pragma unroll
    for (int j = 0; j < 16; ++j) acc[j & 3] += (double)xv[j] * (double)wv[j];
    // fused bf16 conversion: lane with e==ck converts this 16-elem chunk
    if (e == ck) {
      unsigned int w[8];
#pragma unroll
      for (int j = 0; j < 8; ++j)
        w[j] = (unsigned)f2bf(xv[2 * j]) | ((unsigned)f2bf(xv[2 * j + 1]) << 16);
      uint4* dp = (uint4*)(xdst + ck * 16);
      dp[0] = make_uint4(w[0], w[1], w[2], w[3]);
      dp[1] = make_uint4(w[4], w[5], w[6], w[7]);
    }
  }
  double s = (acc[0] + acc[1]) + (acc[2] + acc[3]);
  // sum over stripes g (lane bits 3,4,5)
  s += __shfl_xor(s, 8);
  s += __shfl_xor(s, 16);
  s += __shfl_xor(s, 32);
  s += (double)rb[e];
  // parallel max/argmax over experts e (lane bits 0,1,2); first-index ties like np.argmax
  double bv = s;
  int bi = e;
#pragma unroll
  for (int mask = 1; mask <= 4; mask <<= 1) {
    double ov = __shfl_xor(bv, mask);
    int oi = __shfl_xor(bi, mask);
    if (ov > bv || (ov == bv && oi < bi)) { bv = ov; bi = oi; }
  }
  if (lane == 0) {
    int pos = atomicAdd(&counts[bi], 1);
    tok[(bi << 14) + pos] = n;
  }
}

// Grouped GEMM: C[m, o] = sum_d Xg[m, d] * W[o, d]  (both K-contiguous, "B^T" form)
// 128x128 tile, BK=64, 4 waves, mfma_f32_16x16x32_bf16.
// grid.x = expert*128 + token_tile, grid.y = output col tile (8).
__global__ __launch_bounds__(256, 2) void k_gemm(const unsigned short* __restrict__ xbf,
                                                 const unsigned short* __restrict__ wbf,
                                                 const float* __restrict__ eb,
                                                 const int* __restrict__ counts,
                                                 const int* __restrict__ tokall,
                                                 float* __restrict__ out) {
  const int e = blockIdx.x >> 7;
  const int t = blockIdx.x & 127;
  const int c = counts[e];
  if (t * 128 >= c) return;
  const int n0 = blockIdx.y << 7;
  const int* tok = tokall + (e << 14);
  const int tid = threadIdx.x;
  const int lane = tid & 63;
  const int wave = tid >> 6;

  __shared__ unsigned short As[128 * 64];  // 16 KB, row stride 128 B, chunk-swizzled
  __shared__ unsigned short Bs[128 * 64];

  // Staging: 4 calls of (32 rows x 8 chunks of 16B). LDS dest is linear
  // (global_load_lds requires it); swizzle applied on the GLOBAL source side:
  // physical chunk p at row r holds logical chunk p ^ (r & 7).
  const int prow = tid >> 3;
  const int pchk = tid & 7;
  size_t asrc[4], bsrc[4];
  const unsigned short* wb = wbf + ((size_t)e << 20);
#pragma unroll
  for (int s = 0; s < 4; ++s) {
    int row = s * 32 + prow;
    int m = t * 128 + row;
    int g = tok[(m < c) ? m : 0];          // pad rows replay token 0 (stores guarded)
    int l = pchk ^ (row & 7);
    asrc[s] = (size_t)g * DIM + (size_t)l * 8;
    bsrc[s] = (size_t)(n0 + row) * DIM + (size_t)l * 8;
  }

  f32x4 acc[4][4] = {};
  const int wr = wave >> 1, wc = wave & 1;

  // LDS read offsets (elements). A-frag: lane holds A[row = lane&15][k = (lane>>4)*8 + j].
  int aoff[2][4], boff[2][4];
#pragma unroll
  for (int h = 0; h < 2; ++h)
#pragma unroll
    for (int m = 0; m < 4; ++m) {
      int row = wr * 64 + m * 16 + (lane & 15);
      int p = (h * 4 + (lane >> 4)) ^ (row & 7);
      aoff[h][m] = row * 64 + p * 8;
      int rowb = wc * 64 + m * 16 + (lane & 15);
      int pb = (h * 4 + (lane >> 4)) ^ (rowb & 7);
      boff[h][m] = rowb * 64 + pb * 8;
    }

  for (int k0 = 0; k0 < DIM; k0 += 64) {
#pragma unroll
    for (int s = 0; s < 4; ++s) {
      __builtin_amdgcn_global_load_lds(
          (const __attribute__((address_space(1))) unsigned int*)(xbf + asrc[s] + k0),
          (__attribute__((address_space(3))) unsigned int*)(&As[s * 2048 + wave * 512]),
          16, 0, 0);
      __builtin_amdgcn_global_load_lds(
          (const __attribute__((address_space(1))) unsigned int*)(wb + bsrc[s] + k0),
          (__attribute__((address_space(3))) unsigned int*)(&Bs[s * 2048 + wave * 512]),
          16, 0, 0);
    }
    __syncthreads();
#pragma unroll
    for (int h = 0; h < 2; ++h) {
      bf16x8 af[4], bfr[4];
#pragma unroll
      for (int m = 0; m < 4; ++m) af[m] = *(const bf16x8*)&As[aoff[h][m]];
#pragma unroll
      for (int n = 0; n < 4; ++n) bfr[n] = *(const bf16x8*)&Bs[boff[h][n]];
#pragma unroll
      for (int m = 0; m < 4; ++m)
#pragma unroll
        for (int n = 0; n < 4; ++n)
          acc[m][n] = __builtin_amdgcn_mfma_f32_16x16x32_bf16(af[m], bfr[n], acc[m][n], 0, 0, 0);
    }
    __syncthreads();
  }

  // Epilogue: C/D layout col = lane&15, row = (lane>>4)*4 + reg. Add bias, scatter to out[token].
  const int colb = n0 + wc * 64 + (lane & 15);
  float bias[4];
#pragma unroll
  for (int n = 0; n < 4; ++n) bias[n] = eb[(e << 10) + colb + n * 16];
#pragma unroll
  for (int m = 0; m < 4; ++m) {
    int rbase = t * 128 + wr * 64 + m * 16 + ((lane >> 4) << 2);
#pragma unroll
    for (int r = 0; r < 4; ++r) {
      int mm = rbase + r;
      if (mm < c) {
        int g = tok[mm];
        float* op = out + ((size_t)g << 10);
#pragma unroll
        for (int n = 0; n < 4; ++n) op[colb + n * 16] = acc[m][n][r] + bias[n];
      }
    }
  }
}

extern "C" void kernel_launch(void* const* d_in, const int* in_sizes, int n_in,
                              void* d_out, int out_size, void* d_ws, size_t ws_size,
                              hipStream_t stream) {
  const float* x  = (const float*)d_in[0];
  const float* rw = (const float*)d_in[1];
  const float* rb = (const float*)d_in[2];
  const float* ew = (const float*)d_in[3];
  const float* eb = (const float*)d_in[4];
  float* out = (float*)d_out;

  char* ws = (char*)d_ws;
  unsigned short* wbf = (unsigned short*)ws;                       // 16 MB
  unsigned short* xbf = (unsigned short*)(ws + (16u << 20));       // 32 MB
  int* tok    = (int*)(ws + (48u << 20));                          // 512 KB
  int* counts = (int*)(ws + (48u << 20) + (1u << 19));             // 32 B

  k_init<<<1, 64, 0, stream>>>(counts);
  k_convw<<<4096, 256, 0, stream>>>(ew, wbf);                       // 8M elems / 8 per thread
  k_router<<<NTOK / 4, 256, 0, stream>>>(x, rw, rb, xbf, counts, tok);
  k_gemm<<<dim3(NEXP * 128, DIM / 128), 256, 0, stream>>>(xbf, wbf, eb, counts, tok, out);
}

// Round 3
// 193.301 us; speedup vs baseline: 1.5146x; 1.5146x over previous
//
#include <hip/hip_runtime.h>
#include <hip/hip_bf16.h>

// MoE top-1: N=16384 tokens, D=1024, E=8 experts.
// out[n] = expert_w[argmax(router(x[n]))] @ x[n] + expert_b[e]
//
// Pipeline: convert W to bf16 -> router (f64 logits, lane-parallel, writes
// top[n], fused x->bf16; NO atomics) -> single-block counting sort (builds
// sorted per-expert token lists + counts) -> grouped bf16-MFMA GEMM.

#define NTOK 16384
#define DIM  1024
#define NEXP 8

typedef __bf16 bf16x8 __attribute__((ext_vector_type(8)));
typedef float  f32x4  __attribute__((ext_vector_type(4)));

__device__ __forceinline__ unsigned short f2bf(float f) {
  unsigned int u = __builtin_bit_cast(unsigned int, f);
  u += 0x7FFFu + ((u >> 16) & 1u);   // round-to-nearest-even (finite inputs)
  return (unsigned short)(u >> 16);
}

// expert_w f32 -> bf16, 8 elements per thread. grid 4096 x 256.
__global__ __launch_bounds__(256) void k_convw(const float* __restrict__ src,
                                               unsigned short* __restrict__ dst) {
  size_t i = ((size_t)blockIdx.x * 256 + threadIdx.x) * 8;
  const float4* p = (const float4*)(src + i);
  float4 a = p[0], b = p[1];
  unsigned int w0 = (unsigned)f2bf(a.x) | ((unsigned)f2bf(a.y) << 16);
  unsigned int w1 = (unsigned)f2bf(a.z) | ((unsigned)f2bf(a.w) << 16);
  unsigned int w2 = (unsigned)f2bf(b.x) | ((unsigned)f2bf(b.y) << 16);
  unsigned int w3 = (unsigned)f2bf(b.z) | ((unsigned)f2bf(b.w) << 16);
  *(uint4*)(dst + i) = make_uint4(w0, w1, w2, w3);
}

// Router: one wave per token. lane = (g<<3)|e : expert e in [0,8), stripe g in [0,8).
// Lane accumulates sum_{d in stripe g} x[n][d]*rw[e][d] in f64 (4 accumulators),
// butterfly-sum over g (xor 8,16,32), then parallel max/argmax over e (xor 1,2,4).
// f64 accumulation => argmax matches exact logits. Writes top[n] only (no atomics).
// Fused: x -> bf16 (lane (g,e) converts chunk e of stripe g).
__global__ __launch_bounds__(256) void k_router(const float* __restrict__ x,
                                                const float* __restrict__ rw,
                                                const float* __restrict__ rb,
                                                unsigned short* __restrict__ xbf,
                                                int* __restrict__ top) {
  const int lane = threadIdx.x & 63;
  const int wave = threadIdx.x >> 6;
  const int n = (blockIdx.x << 2) + wave;
  const int e = lane & 7;
  const int g = lane >> 3;

  const float* xrow = x + (size_t)n * DIM + g * 128;
  const float* wrow = rw + (e << 10) + g * 128;
  unsigned short* xdst = xbf + (size_t)n * DIM + g * 128;

  double acc[4] = {0.0, 0.0, 0.0, 0.0};
#pragma unroll
  for (int ck = 0; ck < 8; ++ck) {
    float xv[16], wv[16];
    const float4* xp = (const float4*)(xrow + ck * 16);
    const float4* wp = (const float4*)(wrow + ck * 16);
#pragma unroll
    for (int i = 0; i < 4; ++i) *(float4*)&xv[i * 4] = xp[i];
#pragma unroll
    for (int i = 0; i < 4; ++i) *(float4*)&wv[i * 4] = wp[i];
#pragma unroll
    for (int j = 0; j < 16; ++j) acc[j & 3] += (double)xv[j] * (double)wv[j];
    // fused bf16 conversion: lane with e==ck converts this 16-elem chunk
    if (e == ck) {
      unsigned int w[8];
#pragma unroll
      for (int j = 0; j < 8; ++j)
        w[j] = (unsigned)f2bf(xv[2 * j]) | ((unsigned)f2bf(xv[2 * j + 1]) << 16);
      uint4* dp = (uint4*)(xdst + ck * 16);
      dp[0] = make_uint4(w[0], w[1], w[2], w[3]);
      dp[1] = make_uint4(w[4], w[5], w[6], w[7]);
    }
  }
  double s = (acc[0] + acc[1]) + (acc[2] + acc[3]);
  // sum over stripes g (lane bits 3,4,5)
  s += __shfl_xor(s, 8);
  s += __shfl_xor(s, 16);
  s += __shfl_xor(s, 32);
  s += (double)rb[e];
  // parallel max/argmax over experts e (lane bits 0,1,2); first-index ties like np.argmax
  double bv = s;
  int bi = e;
#pragma unroll
  for (int mask = 1; mask <= 4; mask <<= 1) {
    double ov = __shfl_xor(bv, mask);
    int oi = __shfl_xor(bi, mask);
    if (ov > bv || (ov == bv && oi < bi)) { bv = ov; bi = oi; }
  }
  if (lane == 0) top[n] = bi;
}

// Counting sort of 16384 expert ids in ONE block (1024 threads x 16 tokens).
// Per-thread histogram packed as 2x u64 (8 experts x 16-bit fields; max count
// 16384 < 65536 so fields never overflow). Hillis-Steele scan (10 steps) over
// the packed u64s in LDS, then ordered scatter into per-expert token lists.
// Deterministic; lists come out sorted by token index (better GEMM locality).
__global__ __launch_bounds__(1024) void k_sort(const int* __restrict__ top,
                                               int* __restrict__ counts,
                                               int* __restrict__ tok) {
  __shared__ unsigned long long sc[2][2][1024];  // [buf][pack][thread] = 32 KB
  const int t = threadIdx.x;

  int4 v[4];
  const int4* tp = (const int4*)(top + t * 16);
#pragma unroll
  for (int i = 0; i < 4; ++i) v[i] = tp[i];

  unsigned long long h0 = 0, h1 = 0;
#pragma unroll
  for (int i = 0; i < 16; ++i) {
    int e = ((const int*)v)[i];
    if (e < 4) h0 += 1ull << (16 * e);
    else       h1 += 1ull << (16 * (e - 4));
  }
  sc[0][0][t] = h0;
  sc[0][1][t] = h1;
  __syncthreads();

  int cur = 0;
  for (int s = 1; s < 1024; s <<= 1) {
    unsigned long long a0 = sc[cur][0][t], a1 = sc[cur][1][t];
    if (t >= s) { a0 += sc[cur][0][t - s]; a1 += sc[cur][1][t - s]; }
    sc[cur ^ 1][0][t] = a0;
    sc[cur ^ 1][1][t] = a1;
    cur ^= 1;
    __syncthreads();
  }

  // inclusive scan in sc[cur]; exclusive base for this thread = inclusive - own
  unsigned long long b0 = sc[cur][0][t] - h0;
  unsigned long long b1 = sc[cur][1][t] - h1;
  if (t == 1023) {
    unsigned long long i0 = sc[cur][0][t], i1 = sc[cur][1][t];
#pragma unroll
    for (int e = 0; e < 4; ++e) counts[e] = (int)((i0 >> (16 * e)) & 0xFFFF);
#pragma unroll
    for (int e = 0; e < 4; ++e) counts[4 + e] = (int)((i1 >> (16 * e)) & 0xFFFF);
  }
  // ordered scatter; packed-field cursors stay in registers (no runtime-indexed array)
#pragma unroll
  for (int i = 0; i < 16; ++i) {
    int e = ((const int*)v)[i];
    int pos;
    if (e < 4) {
      pos = (int)((b0 >> (16 * e)) & 0xFFFF);
      b0 += 1ull << (16 * e);
    } else {
      int f = e - 4;
      pos = (int)((b1 >> (16 * f)) & 0xFFFF);
      b1 += 1ull << (16 * f);
    }
    tok[(e << 14) + pos] = t * 16 + i;
  }
}

// Grouped GEMM: C[m, o] = sum_d Xg[m, d] * W[o, d]  (both K-contiguous, "B^T" form)
// 128x128 tile, BK=64, 4 waves, mfma_f32_16x16x32_bf16.
// grid.x = expert*128 + token_tile, grid.y = output col tile (8).
__global__ __launch_bounds__(256, 2) void k_gemm(const unsigned short* __restrict__ xbf,
                                                 const unsigned short* __restrict__ wbf,
                                                 const float* __restrict__ eb,
                                                 const int* __restrict__ counts,
                                                 const int* __restrict__ tokall,
                                                 float* __restrict__ out) {
  const int e = blockIdx.x >> 7;
  const int t = blockIdx.x & 127;
  const int c = counts[e];
  if (t * 128 >= c) return;
  const int n0 = blockIdx.y << 7;
  const int* tok = tokall + (e << 14);
  const int tid = threadIdx.x;
  const int lane = tid & 63;
  const int wave = tid >> 6;

  __shared__ unsigned short As[128 * 64];  // 16 KB, row stride 128 B, chunk-swizzled
  __shared__ unsigned short Bs[128 * 64];

  // Staging: 4 calls of (32 rows x 8 chunks of 16B). LDS dest is linear
  // (global_load_lds requires it); swizzle applied on the GLOBAL source side:
  // physical chunk p at row r holds logical chunk p ^ (r & 7).
  const int prow = tid >> 3;
  const int pchk = tid & 7;
  size_t asrc[4], bsrc[4];
  const unsigned short* wb = wbf + ((size_t)e << 20);
#pragma unroll
  for (int s = 0; s < 4; ++s) {
    int row = s * 32 + prow;
    int m = t * 128 + row;
    int g = tok[(m < c) ? m : 0];          // pad rows replay token 0 (stores guarded)
    int l = pchk ^ (row & 7);
    asrc[s] = (size_t)g * DIM + (size_t)l * 8;
    bsrc[s] = (size_t)(n0 + row) * DIM + (size_t)l * 8;
  }

  f32x4 acc[4][4] = {};
  const int wr = wave >> 1, wc = wave & 1;

  // LDS read offsets (elements). A-frag: lane holds A[row = lane&15][k = (lane>>4)*8 + j].
  int aoff[2][4], boff[2][4];
#pragma unroll
  for (int h = 0; h < 2; ++h)
#pragma unroll
    for (int m = 0; m < 4; ++m) {
      int row = wr * 64 + m * 16 + (lane & 15);
      int p = (h * 4 + (lane >> 4)) ^ (row & 7);
      aoff[h][m] = row * 64 + p * 8;
      int rowb = wc * 64 + m * 16 + (lane & 15);
      int pb = (h * 4 + (lane >> 4)) ^ (rowb & 7);
      boff[h][m] = rowb * 64 + pb * 8;
    }

  for (int k0 = 0; k0 < DIM; k0 += 64) {
#pragma unroll
    for (int s = 0; s < 4; ++s) {
      __builtin_amdgcn_global_load_lds(
          (const __attribute__((address_space(1))) unsigned int*)(xbf + asrc[s] + k0),
          (__attribute__((address_space(3))) unsigned int*)(&As[s * 2048 + wave * 512]),
          16, 0, 0);
      __builtin_amdgcn_global_load_lds(
          (const __attribute__((address_space(1))) unsigned int*)(wb + bsrc[s] + k0),
          (__attribute__((address_space(3))) unsigned int*)(&Bs[s * 2048 + wave * 512]),
          16, 0, 0);
    }
    __syncthreads();
#pragma unroll
    for (int h = 0; h < 2; ++h) {
      bf16x8 af[4], bfr[4];
#pragma unroll
      for (int m = 0; m < 4; ++m) af[m] = *(const bf16x8*)&As[aoff[h][m]];
#pragma unroll
      for (int n = 0; n < 4; ++n) bfr[n] = *(const bf16x8*)&Bs[boff[h][n]];
#pragma unroll
      for (int m = 0; m < 4; ++m)
#pragma unroll
        for (int n = 0; n < 4; ++n)
          acc[m][n] = __builtin_amdgcn_mfma_f32_16x16x32_bf16(af[m], bfr[n], acc[m][n], 0, 0, 0);
    }
    __syncthreads();
  }

  // Epilogue: C/D layout col = lane&15, row = (lane>>4)*4 + reg. Add bias, scatter to out[token].
  const int colb = n0 + wc * 64 + (lane & 15);
  float bias[4];
#pragma unroll
  for (int n = 0; n < 4; ++n) bias[n] = eb[(e << 10) + colb + n * 16];
#pragma unroll
  for (int m = 0; m < 4; ++m) {
    int rbase = t * 128 + wr * 64 + m * 16 + ((lane >> 4) << 2);
#pragma unroll
    for (int r = 0; r < 4; ++r) {
      int mm = rbase + r;
      if (mm < c) {
        int g = tok[mm];
        float* op = out + ((size_t)g << 10);
#pragma unroll
        for (int n = 0; n < 4; ++n) op[colb + n * 16] = acc[m][n][r] + bias[n];
      }
    }
  }
}

extern "C" void kernel_launch(void* const* d_in, const int* in_sizes, int n_in,
                              void* d_out, int out_size, void* d_ws, size_t ws_size,
                              hipStream_t stream) {
  const float* x  = (const float*)d_in[0];
  const float* rw = (const float*)d_in[1];
  const float* rb = (const float*)d_in[2];
  const float* ew = (const float*)d_in[3];
  const float* eb = (const float*)d_in[4];
  float* out = (float*)d_out;

  char* ws = (char*)d_ws;
  unsigned short* wbf = (unsigned short*)ws;                         // 16 MB
  unsigned short* xbf = (unsigned short*)(ws + (16u << 20));         // 32 MB
  int* tok    = (int*)(ws + (48u << 20));                            // 512 KB
  int* counts = (int*)(ws + (48u << 20) + (1u << 19));               // 32 B
  int* top    = (int*)(ws + (48u << 20) + (1u << 19) + 128);         // 64 KB

  k_convw<<<4096, 256, 0, stream>>>(ew, wbf);                        // 8M elems / 8 per thread
  k_router<<<NTOK / 4, 256, 0, stream>>>(x, rw, rb, xbf, top);
  k_sort<<<1, 1024, 0, stream>>>(top, counts, tok);
  k_gemm<<<dim3(NEXP * 128, DIM / 128), 256, 0, stream>>>(xbf, wbf, eb, counts, tok, out);
}

// Round 4
// 179.023 us; speedup vs baseline: 1.6354x; 1.0798x over previous
//
#include <hip/hip_runtime.h>
#include <hip/hip_bf16.h>

// MoE top-1: N=16384 tokens, D=1024, E=8 experts.
// out[n] = expert_w[argmax(router(x[n]))] @ x[n] + expert_b[e]
//
// Pipeline: convert W to bf16 -> router (lane=(token,expert), full dot per
// lane, f64-exact accumulate, fused x->bf16, writes top[n]; no atomics) ->
// single-block counting sort -> grouped bf16-MFMA GEMM.

#define NTOK 16384
#define DIM  1024
#define NEXP 8

typedef __bf16 bf16x8 __attribute__((ext_vector_type(8)));
typedef float  f32x4  __attribute__((ext_vector_type(4)));

__device__ __forceinline__ unsigned short f2bf(float f) {
  unsigned int u = __builtin_bit_cast(unsigned int, f);
  u += 0x7FFFu + ((u >> 16) & 1u);   // round-to-nearest-even (finite inputs)
  return (unsigned short)(u >> 16);
}

// expert_w f32 -> bf16, 8 elements per thread. grid 4096 x 256.
__global__ __launch_bounds__(256) void k_convw(const float* __restrict__ src,
                                               unsigned short* __restrict__ dst) {
  size_t i = ((size_t)blockIdx.x * 256 + threadIdx.x) * 8;
  const float4* p = (const float4*)(src + i);
  float4 a = p[0], b = p[1];
  unsigned int w0 = (unsigned)f2bf(a.x) | ((unsigned)f2bf(a.y) << 16);
  unsigned int w1 = (unsigned)f2bf(a.z) | ((unsigned)f2bf(a.w) << 16);
  unsigned int w2 = (unsigned)f2bf(b.x) | ((unsigned)f2bf(b.y) << 16);
  unsigned int w3 = (unsigned)f2bf(b.z) | ((unsigned)f2bf(b.w) << 16);
  *(uint4*)(dst + i) = make_uint4(w0, w1, w2, w3);
}

// Router: lane = (t<<3)|e -> 8 tokens/wave, each lane computes the FULL
// 1024-term dot for (token t, expert e). f32 products are exact in f64;
// f64 adds => logits are ground-truth => argmax matches exact logits.
// All loads independent (deep MLP); x float4s broadcast across the 8
// expert lanes. Fused x->bf16: lane e converts pair-chunks p with p&7==e.
__global__ __launch_bounds__(256) void k_router(const float* __restrict__ x,
                                                const float* __restrict__ rw,
                                                const float* __restrict__ rb,
                                                unsigned short* __restrict__ xbf,
                                                int* __restrict__ top) {
  const int lane = threadIdx.x & 63;
  const int wave = threadIdx.x >> 6;
  const int e = lane & 7;
  const int n = (blockIdx.x << 5) + (wave << 3) + (lane >> 3);

  const float4* xp = (const float4*)(x + ((size_t)n << 10));
  const float4* wp = (const float4*)(rw + (e << 10));
  unsigned short* xd = xbf + ((size_t)n << 10);

  double a0 = 0.0, a1 = 0.0, a2 = 0.0, a3 = 0.0;
#pragma unroll 4
  for (int p = 0; p < 128; ++p) {   // pair-chunk p = elements [8p, 8p+8)
    float4 u = xp[2 * p], v = xp[2 * p + 1];
    float4 wu = wp[2 * p], wv = wp[2 * p + 1];
    a0 += (double)u.x * (double)wu.x;
    a1 += (double)u.y * (double)wu.y;
    a2 += (double)u.z * (double)wu.z;
    a3 += (double)u.w * (double)wu.w;
    a0 += (double)v.x * (double)wv.x;
    a1 += (double)v.y * (double)wv.y;
    a2 += (double)v.z * (double)wv.z;
    a3 += (double)v.w * (double)wv.w;
    if ((p & 7) == e) {   // fused bf16 conversion of this 8-elem chunk
      unsigned int c0 = (unsigned)f2bf(u.x) | ((unsigned)f2bf(u.y) << 16);
      unsigned int c1 = (unsigned)f2bf(u.z) | ((unsigned)f2bf(u.w) << 16);
      unsigned int c2 = (unsigned)f2bf(v.x) | ((unsigned)f2bf(v.y) << 16);
      unsigned int c3 = (unsigned)f2bf(v.z) | ((unsigned)f2bf(v.w) << 16);
      *(uint4*)(xd + 8 * p) = make_uint4(c0, c1, c2, c3);
    }
  }
  double s = (a0 + a1) + (a2 + a3);
  s += (double)rb[e];
  // argmax over the 8 expert lanes (xor 1,2,4 stays in-group); first index on ties
  double bv = s;
  int bi = e;
#pragma unroll
  for (int mask = 1; mask <= 4; mask <<= 1) {
    double ov = __shfl_xor(bv, mask);
    int oi = __shfl_xor(bi, mask);
    if (ov > bv || (ov == bv && oi < bi)) { bv = ov; bi = oi; }
  }
  if (e == 0) top[n] = bi;
}

// Counting sort of 16384 expert ids in ONE block (1024 threads x 16 tokens).
// Per-thread histogram packed as 2x u64 (8 experts x 16-bit fields; max count
// 16384 < 65536 so fields never overflow). Hillis-Steele scan (10 steps) over
// the packed u64s in LDS, then ordered scatter into per-expert token lists.
// Deterministic; lists come out sorted by token index (better GEMM locality).
__global__ __launch_bounds__(1024) void k_sort(const int* __restrict__ top,
                                               int* __restrict__ counts,
                                               int* __restrict__ tok) {
  __shared__ unsigned long long sc[2][2][1024];  // [buf][pack][thread] = 32 KB
  const int t = threadIdx.x;

  int4 v[4];
  const int4* tp = (const int4*)(top + t * 16);
#pragma unroll
  for (int i = 0; i < 4; ++i) v[i] = tp[i];

  unsigned long long h0 = 0, h1 = 0;
#pragma unroll
  for (int i = 0; i < 16; ++i) {
    int e = ((const int*)v)[i];
    if (e < 4) h0 += 1ull << (16 * e);
    else       h1 += 1ull << (16 * (e - 4));
  }
  sc[0][0][t] = h0;
  sc[0][1][t] = h1;
  __syncthreads();

  int cur = 0;
  for (int s = 1; s < 1024; s <<= 1) {
    unsigned long long a0 = sc[cur][0][t], a1 = sc[cur][1][t];
    if (t >= s) { a0 += sc[cur][0][t - s]; a1 += sc[cur][1][t - s]; }
    sc[cur ^ 1][0][t] = a0;
    sc[cur ^ 1][1][t] = a1;
    cur ^= 1;
    __syncthreads();
  }

  // inclusive scan in sc[cur]; exclusive base for this thread = inclusive - own
  unsigned long long b0 = sc[cur][0][t] - h0;
  unsigned long long b1 = sc[cur][1][t] - h1;
  if (t == 1023) {
    unsigned long long i0 = sc[cur][0][t], i1 = sc[cur][1][t];
#pragma unroll
    for (int e = 0; e < 4; ++e) counts[e] = (int)((i0 >> (16 * e)) & 0xFFFF);
#pragma unroll
    for (int e = 0; e < 4; ++e) counts[4 + e] = (int)((i1 >> (16 * e)) & 0xFFFF);
  }
  // ordered scatter; packed-field cursors stay in registers (no runtime-indexed array)
#pragma unroll
  for (int i = 0; i < 16; ++i) {
    int e = ((const int*)v)[i];
    int pos;
    if (e < 4) {
      pos = (int)((b0 >> (16 * e)) & 0xFFFF);
      b0 += 1ull << (16 * e);
    } else {
      int f = e - 4;
      pos = (int)((b1 >> (16 * f)) & 0xFFFF);
      b1 += 1ull << (16 * f);
    }
    tok[(e << 14) + pos] = t * 16 + i;
  }
}

// Grouped GEMM: C[m, o] = sum_d Xg[m, d] * W[o, d]  (both K-contiguous, "B^T" form)
// 128x128 tile, BK=64, 4 waves, mfma_f32_16x16x32_bf16.
// grid.x = expert*128 + token_tile, grid.y = output col tile (8).
__global__ __launch_bounds__(256, 2) void k_gemm(const unsigned short* __restrict__ xbf,
                                                 const unsigned short* __restrict__ wbf,
                                                 const float* __restrict__ eb,
                                                 const int* __restrict__ counts,
                                                 const int* __restrict__ tokall,
                                                 float* __restrict__ out) {
  const int e = blockIdx.x >> 7;
  const int t = blockIdx.x & 127;
  const int c = counts[e];
  if (t * 128 >= c) return;
  const int n0 = blockIdx.y << 7;
  const int* tok = tokall + (e << 14);
  const int tid = threadIdx.x;
  const int lane = tid & 63;
  const int wave = tid >> 6;

  __shared__ unsigned short As[128 * 64];  // 16 KB, row stride 128 B, chunk-swizzled
  __shared__ unsigned short Bs[128 * 64];

  // Staging: 4 calls of (32 rows x 8 chunks of 16B). LDS dest is linear
  // (global_load_lds requires it); swizzle applied on the GLOBAL source side:
  // physical chunk p at row r holds logical chunk p ^ (r & 7).
  const int prow = tid >> 3;
  const int pchk = tid & 7;
  size_t asrc[4], bsrc[4];
  const unsigned short* wb = wbf + ((size_t)e << 20);
#pragma unroll
  for (int s = 0; s < 4; ++s) {
    int row = s * 32 + prow;
    int m = t * 128 + row;
    int g = tok[(m < c) ? m : 0];          // pad rows replay token 0 (stores guarded)
    int l = pchk ^ (row & 7);
    asrc[s] = (size_t)g * DIM + (size_t)l * 8;
    bsrc[s] = (size_t)(n0 + row) * DIM + (size_t)l * 8;
  }

  f32x4 acc[4][4] = {};
  const int wr = wave >> 1, wc = wave & 1;

  // LDS read offsets (elements). A-frag: lane holds A[row = lane&15][k = (lane>>4)*8 + j].
  int aoff[2][4], boff[2][4];
#pragma unroll
  for (int h = 0; h < 2; ++h)
#pragma unroll
    for (int m = 0; m < 4; ++m) {
      int row = wr * 64 + m * 16 + (lane & 15);
      int p = (h * 4 + (lane >> 4)) ^ (row & 7);
      aoff[h][m] = row * 64 + p * 8;
      int rowb = wc * 64 + m * 16 + (lane & 15);
      int pb = (h * 4 + (lane >> 4)) ^ (rowb & 7);
      boff[h][m] = rowb * 64 + pb * 8;
    }

  for (int k0 = 0; k0 < DIM; k0 += 64) {
#pragma unroll
    for (int s = 0; s < 4; ++s) {
      __builtin_amdgcn_global_load_lds(
          (const __attribute__((address_space(1))) unsigned int*)(xbf + asrc[s] + k0),
          (__attribute__((address_space(3))) unsigned int*)(&As[s * 2048 + wave * 512]),
          16, 0, 0);
      __builtin_amdgcn_global_load_lds(
          (const __attribute__((address_space(1))) unsigned int*)(wb + bsrc[s] + k0),
          (__attribute__((address_space(3))) unsigned int*)(&Bs[s * 2048 + wave * 512]),
          16, 0, 0);
    }
    __syncthreads();
#pragma unroll
    for (int h = 0; h < 2; ++h) {
      bf16x8 af[4], bfr[4];
#pragma unroll
      for (int m = 0; m < 4; ++m) af[m] = *(const bf16x8*)&As[aoff[h][m]];
#pragma unroll
      for (int n = 0; n < 4; ++n) bfr[n] = *(const bf16x8*)&Bs[boff[h][n]];
#pragma unroll
      for (int m = 0; m < 4; ++m)
#pragma unroll
        for (int n = 0; n < 4; ++n)
          acc[m][n] = __builtin_amdgcn_mfma_f32_16x16x32_bf16(af[m], bfr[n], acc[m][n], 0, 0, 0);
    }
    __syncthreads();
  }

  // Epilogue: C/D layout col = lane&15, row = (lane>>4)*4 + reg. Add bias, scatter to out[token].
  const int colb = n0 + wc * 64 + (lane & 15);
  float bias[4];
#pragma unroll
  for (int n = 0; n < 4; ++n) bias[n] = eb[(e << 10) + colb + n * 16];
#pragma unroll
  for (int m = 0; m < 4; ++m) {
    int rbase = t * 128 + wr * 64 + m * 16 + ((lane >> 4) << 2);
#pragma unroll
    for (int r = 0; r < 4; ++r) {
      int mm = rbase + r;
      if (mm < c) {
        int g = tok[mm];
        float* op = out + ((size_t)g << 10);
#pragma unroll
        for (int n = 0; n < 4; ++n) op[colb + n * 16] = acc[m][n][r] + bias[n];
      }
    }
  }
}

extern "C" void kernel_launch(void* const* d_in, const int* in_sizes, int n_in,
                              void* d_out, int out_size, void* d_ws, size_t ws_size,
                              hipStream_t stream) {
  const float* x  = (const float*)d_in[0];
  const float* rw = (const float*)d_in[1];
  const float* rb = (const float*)d_in[2];
  const float* ew = (const float*)d_in[3];
  const float* eb = (const float*)d_in[4];
  float* out = (float*)d_out;

  char* ws = (char*)d_ws;
  unsigned short* wbf = (unsigned short*)ws;                         // 16 MB
  unsigned short* xbf = (unsigned short*)(ws + (16u << 20));         // 32 MB
  int* tok    = (int*)(ws + (48u << 20));                            // 512 KB
  int* counts = (int*)(ws + (48u << 20) + (1u << 19));               // 32 B
  int* top    = (int*)(ws + (48u << 20) + (1u << 19) + 128);         // 64 KB

  k_convw<<<4096, 256, 0, stream>>>(ew, wbf);                        // 8M elems / 8 per thread
  k_router<<<NTOK / 32, 256, 0, stream>>>(x, rw, rb, xbf, top);      // 512 blocks, 8 tok/wave
  k_sort<<<1, 1024, 0, stream>>>(top, counts, tok);
  k_gemm<<<dim3(NEXP * 128, DIM / 128), 256, 0, stream>>>(xbf, wbf, eb, counts, tok, out);
}

// Round 5
// 169.683 us; speedup vs baseline: 1.7254x; 1.0550x over previous
//
#include <hip/hip_runtime.h>
#include <hip/hip_bf16.h>

// MoE top-1: N=16384 tokens, D=1024, E=8 experts.
// out[n] = expert_w[argmax(router(x[n]))] @ x[n] + expert_b[e]
//
// Pipeline: convert W to bf16 -> router (lane=(token,quarter,expert), f64-exact
// quarter-dots + 5 shuffles, fused x->bf16, writes top[n]; no atomics) ->
// single-block counting sort -> grouped bf16-MFMA GEMM.

#define NTOK 16384
#define DIM  1024
#define NEXP 8

typedef __bf16 bf16x8 __attribute__((ext_vector_type(8)));
typedef float  f32x4  __attribute__((ext_vector_type(4)));

__device__ __forceinline__ unsigned short f2bf(float f) {
  unsigned int u = __builtin_bit_cast(unsigned int, f);
  u += 0x7FFFu + ((u >> 16) & 1u);   // round-to-nearest-even (finite inputs)
  return (unsigned short)(u >> 16);
}

// expert_w f32 -> bf16, 8 elements per thread. grid 4096 x 256.
__global__ __launch_bounds__(256) void k_convw(const float* __restrict__ src,
                                               unsigned short* __restrict__ dst) {
  size_t i = ((size_t)blockIdx.x * 256 + threadIdx.x) * 8;
  const float4* p = (const float4*)(src + i);
  float4 a = p[0], b = p[1];
  unsigned int w0 = (unsigned)f2bf(a.x) | ((unsigned)f2bf(a.y) << 16);
  unsigned int w1 = (unsigned)f2bf(a.z) | ((unsigned)f2bf(a.w) << 16);
  unsigned int w2 = (unsigned)f2bf(b.x) | ((unsigned)f2bf(b.y) << 16);
  unsigned int w3 = (unsigned)f2bf(b.z) | ((unsigned)f2bf(b.w) << 16);
  *(uint4*)(dst + i) = make_uint4(w0, w1, w2, w3);
}

// Router: lane = t*32 + g*8 + e (t: token-in-wave 0..1, g: D-quarter 0..3,
// e: expert 0..7). Each lane computes a 256-term dot for (token, expert) over
// quarter g; f32 products are exact in f64 => logits ground-truth => argmax
// exact. Quarter sums combine via xor-shuffle (8,16); argmax over e-lanes via
// xor-shuffle (1,2,4). 2 tokens/wave -> 8192 waves (4x round-3 occupancy).
// Fused x->bf16: lane (t,g,e) converts pair-chunks p of its quarter, p&7==e.
__global__ __launch_bounds__(256) void k_router(const float* __restrict__ x,
                                                const float* __restrict__ rw,
                                                const float* __restrict__ rb,
                                                unsigned short* __restrict__ xbf,
                                                int* __restrict__ top) {
  const int lane = threadIdx.x & 63;
  const int wave = threadIdx.x >> 6;
  const int e = lane & 7;
  const int g = (lane >> 3) & 3;
  const int tl = lane >> 5;
  const int n = (blockIdx.x << 3) + (wave << 1) + tl;

  const float4* xp = (const float4*)(x + ((size_t)n << 10) + (g << 8));
  const float4* wp = (const float4*)(rw + (e << 10) + (g << 8));
  unsigned short* xd = xbf + ((size_t)n << 10) + (g << 8);

  double a0 = 0.0, a1 = 0.0, a2 = 0.0, a3 = 0.0;
#pragma unroll 4
  for (int p = 0; p < 32; ++p) {   // pair-chunk p = quarter elements [8p, 8p+8)
    float4 u = xp[2 * p], v = xp[2 * p + 1];
    float4 wu = wp[2 * p], wv = wp[2 * p + 1];
    a0 += (double)u.x * (double)wu.x;
    a1 += (double)u.y * (double)wu.y;
    a2 += (double)u.z * (double)wu.z;
    a3 += (double)u.w * (double)wu.w;
    a0 += (double)v.x * (double)wv.x;
    a1 += (double)v.y * (double)wv.y;
    a2 += (double)v.z * (double)wv.z;
    a3 += (double)v.w * (double)wv.w;
    if ((p & 7) == e) {   // fused bf16 conversion of this 8-elem chunk
      unsigned int c0 = (unsigned)f2bf(u.x) | ((unsigned)f2bf(u.y) << 16);
      unsigned int c1 = (unsigned)f2bf(u.z) | ((unsigned)f2bf(u.w) << 16);
      unsigned int c2 = (unsigned)f2bf(v.x) | ((unsigned)f2bf(v.y) << 16);
      unsigned int c3 = (unsigned)f2bf(v.z) | ((unsigned)f2bf(v.w) << 16);
      *(uint4*)(xd + 8 * p) = make_uint4(c0, c1, c2, c3);
    }
  }
  double s = (a0 + a1) + (a2 + a3);
  // sum the 4 quarters (g = lane bits 3,4)
  s += __shfl_xor(s, 8);
  s += __shfl_xor(s, 16);
  s += (double)rb[e];
  // argmax over the 8 expert lanes (bits 0-2); first index on ties (np.argmax)
  double bv = s;
  int bi = e;
#pragma unroll
  for (int mask = 1; mask <= 4; mask <<= 1) {
    double ov = __shfl_xor(bv, mask);
    int oi = __shfl_xor(bi, mask);
    if (ov > bv || (ov == bv && oi < bi)) { bv = ov; bi = oi; }
  }
  if ((lane & 31) == 0) top[n] = bi;
}

// Counting sort of 16384 expert ids in ONE block (1024 threads x 16 tokens).
// Per-thread histogram packed as 2x u64 (8 experts x 16-bit fields; max count
// 16384 < 65536 so fields never overflow). Hillis-Steele scan (10 steps) over
// the packed u64s in LDS, then ordered scatter into per-expert token lists.
// Deterministic; lists come out sorted by token index (better GEMM locality).
__global__ __launch_bounds__(1024) void k_sort(const int* __restrict__ top,
                                               int* __restrict__ counts,
                                               int* __restrict__ tok) {
  __shared__ unsigned long long sc[2][2][1024];  // [buf][pack][thread] = 32 KB
  const int t = threadIdx.x;

  int4 v[4];
  const int4* tp = (const int4*)(top + t * 16);
#pragma unroll
  for (int i = 0; i < 4; ++i) v[i] = tp[i];

  unsigned long long h0 = 0, h1 = 0;
#pragma unroll
  for (int i = 0; i < 16; ++i) {
    int e = ((const int*)v)[i];
    if (e < 4) h0 += 1ull << (16 * e);
    else       h1 += 1ull << (16 * (e - 4));
  }
  sc[0][0][t] = h0;
  sc[0][1][t] = h1;
  __syncthreads();

  int cur = 0;
  for (int s = 1; s < 1024; s <<= 1) {
    unsigned long long a0 = sc[cur][0][t], a1 = sc[cur][1][t];
    if (t >= s) { a0 += sc[cur][0][t - s]; a1 += sc[cur][1][t - s]; }
    sc[cur ^ 1][0][t] = a0;
    sc[cur ^ 1][1][t] = a1;
    cur ^= 1;
    __syncthreads();
  }

  // inclusive scan in sc[cur]; exclusive base for this thread = inclusive - own
  unsigned long long b0 = sc[cur][0][t] - h0;
  unsigned long long b1 = sc[cur][1][t] - h1;
  if (t == 1023) {
    unsigned long long i0 = sc[cur][0][t], i1 = sc[cur][1][t];
#pragma unroll
    for (int e = 0; e < 4; ++e) counts[e] = (int)((i0 >> (16 * e)) & 0xFFFF);
#pragma unroll
    for (int e = 0; e < 4; ++e) counts[4 + e] = (int)((i1 >> (16 * e)) & 0xFFFF);
  }
  // ordered scatter; packed-field cursors stay in registers (no runtime-indexed array)
#pragma unroll
  for (int i = 0; i < 16; ++i) {
    int e = ((const int*)v)[i];
    int pos;
    if (e < 4) {
      pos = (int)((b0 >> (16 * e)) & 0xFFFF);
      b0 += 1ull << (16 * e);
    } else {
      int f = e - 4;
      pos = (int)((b1 >> (16 * f)) & 0xFFFF);
      b1 += 1ull << (16 * f);
    }
    tok[(e << 14) + pos] = t * 16 + i;
  }
}

// Grouped GEMM: C[m, o] = sum_d Xg[m, d] * W[o, d]  (both K-contiguous, "B^T" form)
// 128x128 tile, BK=64, 4 waves, mfma_f32_16x16x32_bf16.
// grid.x = expert*128 + token_tile, grid.y = output col tile (8).
__global__ __launch_bounds__(256, 2) void k_gemm(const unsigned short* __restrict__ xbf,
                                                 const unsigned short* __restrict__ wbf,
                                                 const float* __restrict__ eb,
                                                 const int* __restrict__ counts,
                                                 const int* __restrict__ tokall,
                                                 float* __restrict__ out) {
  const int e = blockIdx.x >> 7;
  const int t = blockIdx.x & 127;
  const int c = counts[e];
  if (t * 128 >= c) return;
  const int n0 = blockIdx.y << 7;
  const int* tok = tokall + (e << 14);
  const int tid = threadIdx.x;
  const int lane = tid & 63;
  const int wave = tid >> 6;

  __shared__ unsigned short As[128 * 64];  // 16 KB, row stride 128 B, chunk-swizzled
  __shared__ unsigned short Bs[128 * 64];

  // Staging: 4 calls of (32 rows x 8 chunks of 16B). LDS dest is linear
  // (global_load_lds requires it); swizzle applied on the GLOBAL source side:
  // physical chunk p at row r holds logical chunk p ^ (r & 7).
  const int prow = tid >> 3;
  const int pchk = tid & 7;
  size_t asrc[4], bsrc[4];
  const unsigned short* wb = wbf + ((size_t)e << 20);
#pragma unroll
  for (int s = 0; s < 4; ++s) {
    int row = s * 32 + prow;
    int m = t * 128 + row;
    int g = tok[(m < c) ? m : 0];          // pad rows replay token 0 (stores guarded)
    int l = pchk ^ (row & 7);
    asrc[s] = (size_t)g * DIM + (size_t)l * 8;
    bsrc[s] = (size_t)(n0 + row) * DIM + (size_t)l * 8;
  }

  f32x4 acc[4][4] = {};
  const int wr = wave >> 1, wc = wave & 1;

  // LDS read offsets (elements). A-frag: lane holds A[row = lane&15][k = (lane>>4)*8 + j].
  int aoff[2][4], boff[2][4];
#pragma unroll
  for (int h = 0; h < 2; ++h)
#pragma unroll
    for (int m = 0; m < 4; ++m) {
      int row = wr * 64 + m * 16 + (lane & 15);
      int p = (h * 4 + (lane >> 4)) ^ (row & 7);
      aoff[h][m] = row * 64 + p * 8;
      int rowb = wc * 64 + m * 16 + (lane & 15);
      int pb = (h * 4 + (lane >> 4)) ^ (rowb & 7);
      boff[h][m] = rowb * 64 + pb * 8;
    }

  for (int k0 = 0; k0 < DIM; k0 += 64) {
#pragma unroll
    for (int s = 0; s < 4; ++s) {
      __builtin_amdgcn_global_load_lds(
          (const __attribute__((address_space(1))) unsigned int*)(xbf + asrc[s] + k0),
          (__attribute__((address_space(3))) unsigned int*)(&As[s * 2048 + wave * 512]),
          16, 0, 0);
      __builtin_amdgcn_global_load_lds(
          (const __attribute__((address_space(1))) unsigned int*)(wb + bsrc[s] + k0),
          (__attribute__((address_space(3))) unsigned int*)(&Bs[s * 2048 + wave * 512]),
          16, 0, 0);
    }
    __syncthreads();
#pragma unroll
    for (int h = 0; h < 2; ++h) {
      bf16x8 af[4], bfr[4];
#pragma unroll
      for (int m = 0; m < 4; ++m) af[m] = *(const bf16x8*)&As[aoff[h][m]];
#pragma unroll
      for (int n = 0; n < 4; ++n) bfr[n] = *(const bf16x8*)&Bs[boff[h][n]];
#pragma unroll
      for (int m = 0; m < 4; ++m)
#pragma unroll
        for (int n = 0; n < 4; ++n)
          acc[m][n] = __builtin_amdgcn_mfma_f32_16x16x32_bf16(af[m], bfr[n], acc[m][n], 0, 0, 0);
    }
    __syncthreads();
  }

  // Epilogue: C/D layout col = lane&15, row = (lane>>4)*4 + reg. Add bias, scatter to out[token].
  const int colb = n0 + wc * 64 + (lane & 15);
  float bias[4];
#pragma unroll
  for (int n = 0; n < 4; ++n) bias[n] = eb[(e << 10) + colb + n * 16];
#pragma unroll
  for (int m = 0; m < 4; ++m) {
    int rbase = t * 128 + wr * 64 + m * 16 + ((lane >> 4) << 2);
#pragma unroll
    for (int r = 0; r < 4; ++r) {
      int mm = rbase + r;
      if (mm < c) {
        int g = tok[mm];
        float* op = out + ((size_t)g << 10);
#pragma unroll
        for (int n = 0; n < 4; ++n) op[colb + n * 16] = acc[m][n][r] + bias[n];
      }
    }
  }
}

extern "C" void kernel_launch(void* const* d_in, const int* in_sizes, int n_in,
                              void* d_out, int out_size, void* d_ws, size_t ws_size,
                              hipStream_t stream) {
  const float* x  = (const float*)d_in[0];
  const float* rw = (const float*)d_in[1];
  const float* rb = (const float*)d_in[2];
  const float* ew = (const float*)d_in[3];
  const float* eb = (const float*)d_in[4];
  float* out = (float*)d_out;

  char* ws = (char*)d_ws;
  unsigned short* wbf = (unsigned short*)ws;                         // 16 MB
  unsigned short* xbf = (unsigned short*)(ws + (16u << 20));         // 32 MB
  int* tok    = (int*)(ws + (48u << 20));                            // 512 KB
  int* counts = (int*)(ws + (48u << 20) + (1u << 19));               // 32 B
  int* top    = (int*)(ws + (48u << 20) + (1u << 19) + 128);         // 64 KB

  k_convw<<<4096, 256, 0, stream>>>(ew, wbf);                        // 8M elems / 8 per thread
  k_router<<<NTOK / 8, 256, 0, stream>>>(x, rw, rb, xbf, top);       // 2048 blocks, 2 tok/wave
  k_sort<<<1, 1024, 0, stream>>>(top, counts, tok);
  k_gemm<<<dim3(NEXP * 128, DIM / 128), 256, 0, stream>>>(xbf, wbf, eb, counts, tok, out);
}

// Round 6
// 134.222 us; speedup vs baseline: 2.1813x; 1.2642x over previous
//
#include <hip/hip_runtime.h>
#include <hip/hip_bf16.h>

// MoE top-1: N=16384 tokens, D=1024, E=8 experts.
// out[n] = expert_w[argmax(router(x[n]))] @ x[n] + expert_b[e]
//
// Pipeline: convert W to bf16 -> router (rw staged in LDS, one token per wave,
// lane-unique x slices read ONCE, f64-exact logits, shuffle reduce + argmax,
// fused x->bf16, writes top[n]; no atomics) -> single-block counting sort ->
// grouped bf16-MFMA GEMM.

#define NTOK 16384
#define DIM  1024
#define NEXP 8

typedef __bf16 bf16x8 __attribute__((ext_vector_type(8)));
typedef float  f32x4  __attribute__((ext_vector_type(4)));

__device__ __forceinline__ unsigned short f2bf(float f) {
  unsigned int u = __builtin_bit_cast(unsigned int, f);
  u += 0x7FFFu + ((u >> 16) & 1u);   // round-to-nearest-even (finite inputs)
  return (unsigned short)(u >> 16);
}

// expert_w f32 -> bf16, 8 elements per thread. grid 4096 x 256.
__global__ __launch_bounds__(256) void k_convw(const float* __restrict__ src,
                                               unsigned short* __restrict__ dst) {
  size_t i = ((size_t)blockIdx.x * 256 + threadIdx.x) * 8;
  const float4* p = (const float4*)(src + i);
  float4 a = p[0], b = p[1];
  unsigned int w0 = (unsigned)f2bf(a.x) | ((unsigned)f2bf(a.y) << 16);
  unsigned int w1 = (unsigned)f2bf(a.z) | ((unsigned)f2bf(a.w) << 16);
  unsigned int w2 = (unsigned)f2bf(b.x) | ((unsigned)f2bf(b.y) << 16);
  unsigned int w3 = (unsigned)f2bf(b.z) | ((unsigned)f2bf(b.w) << 16);
  *(uint4*)(dst + i) = make_uint4(w0, w1, w2, w3);
}

// Router: rw (32 KB) staged in LDS once per block. One wave = one token
// (4 tokens/wave via t-loop). Lane l owns x elems {j*256 + 4l .. +4}, j=0..3:
// x read ONCE per byte, coalesced float4 loads. 128 f64 FMAs/lane against the
// 8 experts' LDS chunks (f32 products exact in f64 => argmax exact). Reduce:
// xor{1,2,4} on 8 partials (subgroup sums) -> static select of expert lane&7
// -> xor{8,16,32} -> logits; argmax via xor{1,2,4} compare. Fused x->bf16.
__global__ __launch_bounds__(256) void k_router(const float* __restrict__ x,
                                                const float* __restrict__ rw,
                                                const float* __restrict__ rb,
                                                unsigned short* __restrict__ xbf,
                                                int* __restrict__ top) {
  __shared__ float wlds[NEXP * DIM];   // 32 KB
  const int tid = threadIdx.x;
  const int lane = tid & 63;
  const int wave = tid >> 6;
#pragma unroll
  for (int i = 0; i < 8; ++i)
    ((float4*)wlds)[tid + 256 * i] = ((const float4*)rw)[tid + 256 * i];
  __syncthreads();

  const int ea = lane & 7;
#pragma unroll 1
  for (int t = 0; t < 4; ++t) {
    const int n = (blockIdx.x << 4) + (wave << 2) + t;
    const float4* xp = (const float4*)(x + ((size_t)n << 10)) + lane;
    float4 xv[4];
#pragma unroll
    for (int j = 0; j < 4; ++j) xv[j] = xp[j * 64];   // coalesced, lane-unique

    // fused bf16 conversion + store (8 B/lane/chunk, coalesced)
#pragma unroll
    for (int j = 0; j < 4; ++j) {
      unsigned int c0 = (unsigned)f2bf(xv[j].x) | ((unsigned)f2bf(xv[j].y) << 16);
      unsigned int c1 = (unsigned)f2bf(xv[j].z) | ((unsigned)f2bf(xv[j].w) << 16);
      *(uint2*)(xbf + ((size_t)n << 10) + j * 256 + lane * 4) = make_uint2(c0, c1);
    }

    double p[8] = {};
#pragma unroll
    for (int e = 0; e < 8; ++e)
#pragma unroll
      for (int j = 0; j < 4; ++j) {
        float4 wv = *(const float4*)&wlds[e * 1024 + j * 256 + lane * 4];
        p[e] += (double)xv[j].x * (double)wv.x;
        p[e] += (double)xv[j].y * (double)wv.y;
        p[e] += (double)xv[j].z * (double)wv.z;
        p[e] += (double)xv[j].w * (double)wv.w;
      }

    // subgroup (8-lane) sums of all 8 partials
#pragma unroll
    for (int e = 0; e < 8; ++e) {
      p[e] += __shfl_xor(p[e], 1);
      p[e] += __shfl_xor(p[e], 2);
      p[e] += __shfl_xor(p[e], 4);
    }
    // static select tree: s = p[ea] without runtime indexing (rule #20)
    double q0 = (ea & 1) ? p[1] : p[0];
    double q1 = (ea & 1) ? p[3] : p[2];
    double q2 = (ea & 1) ? p[5] : p[4];
    double q3 = (ea & 1) ? p[7] : p[6];
    double r0 = (ea & 2) ? q1 : q0;
    double r1 = (ea & 2) ? q3 : q2;
    double s  = (ea & 4) ? r1 : r0;
    // sum across the 8 subgroups
    s += __shfl_xor(s, 8);
    s += __shfl_xor(s, 16);
    s += __shfl_xor(s, 32);
    s += (double)rb[ea];
    // argmax over experts (lane bits 0-2); first index on ties (np.argmax)
    double bv = s;
    int bi = ea;
#pragma unroll
    for (int mask = 1; mask <= 4; mask <<= 1) {
      double ov = __shfl_xor(bv, mask);
      int oi = __shfl_xor(bi, mask);
      if (ov > bv || (ov == bv && oi < bi)) { bv = ov; bi = oi; }
    }
    if (lane == 0) top[n] = bi;
  }
}

// Counting sort of 16384 expert ids in ONE block (1024 threads x 16 tokens).
// Per-thread histogram packed as 2x u64 (8 experts x 16-bit fields; max count
// 16384 < 65536 so fields never overflow). Hillis-Steele scan (10 steps) over
// the packed u64s in LDS, then ordered scatter into per-expert token lists.
// Deterministic; lists come out sorted by token index (better GEMM locality).
__global__ __launch_bounds__(1024) void k_sort(const int* __restrict__ top,
                                               int* __restrict__ counts,
                                               int* __restrict__ tok) {
  __shared__ unsigned long long sc[2][2][1024];  // [buf][pack][thread] = 32 KB
  const int t = threadIdx.x;

  int4 v[4];
  const int4* tp = (const int4*)(top + t * 16);
#pragma unroll
  for (int i = 0; i < 4; ++i) v[i] = tp[i];

  unsigned long long h0 = 0, h1 = 0;
#pragma unroll
  for (int i = 0; i < 16; ++i) {
    int e = ((const int*)v)[i];
    if (e < 4) h0 += 1ull << (16 * e);
    else       h1 += 1ull << (16 * (e - 4));
  }
  sc[0][0][t] = h0;
  sc[0][1][t] = h1;
  __syncthreads();

  int cur = 0;
  for (int s = 1; s < 1024; s <<= 1) {
    unsigned long long a0 = sc[cur][0][t], a1 = sc[cur][1][t];
    if (t >= s) { a0 += sc[cur][0][t - s]; a1 += sc[cur][1][t - s]; }
    sc[cur ^ 1][0][t] = a0;
    sc[cur ^ 1][1][t] = a1;
    cur ^= 1;
    __syncthreads();
  }

  // inclusive scan in sc[cur]; exclusive base for this thread = inclusive - own
  unsigned long long b0 = sc[cur][0][t] - h0;
  unsigned long long b1 = sc[cur][1][t] - h1;
  if (t == 1023) {
    unsigned long long i0 = sc[cur][0][t], i1 = sc[cur][1][t];
#pragma unroll
    for (int e = 0; e < 4; ++e) counts[e] = (int)((i0 >> (16 * e)) & 0xFFFF);
#pragma unroll
    for (int e = 0; e < 4; ++e) counts[4 + e] = (int)((i1 >> (16 * e)) & 0xFFFF);
  }
  // ordered scatter; packed-field cursors stay in registers (no runtime-indexed array)
#pragma unroll
  for (int i = 0; i < 16; ++i) {
    int e = ((const int*)v)[i];
    int pos;
    if (e < 4) {
      pos = (int)((b0 >> (16 * e)) & 0xFFFF);
      b0 += 1ull << (16 * e);
    } else {
      int f = e - 4;
      pos = (int)((b1 >> (16 * f)) & 0xFFFF);
      b1 += 1ull << (16 * f);
    }
    tok[(e << 14) + pos] = t * 16 + i;
  }
}

// Grouped GEMM: C[m, o] = sum_d Xg[m, d] * W[o, d]  (both K-contiguous, "B^T" form)
// 128x128 tile, BK=64, 4 waves, mfma_f32_16x16x32_bf16.
// grid.x = expert*128 + token_tile, grid.y = output col tile (8).
__global__ __launch_bounds__(256, 2) void k_gemm(const unsigned short* __restrict__ xbf,
                                                 const unsigned short* __restrict__ wbf,
                                                 const float* __restrict__ eb,
                                                 const int* __restrict__ counts,
                                                 const int* __restrict__ tokall,
                                                 float* __restrict__ out) {
  const int e = blockIdx.x >> 7;
  const int t = blockIdx.x & 127;
  const int c = counts[e];
  if (t * 128 >= c) return;
  const int n0 = blockIdx.y << 7;
  const int* tok = tokall + (e << 14);
  const int tid = threadIdx.x;
  const int lane = tid & 63;
  const int wave = tid >> 6;

  __shared__ unsigned short As[128 * 64];  // 16 KB, row stride 128 B, chunk-swizzled
  __shared__ unsigned short Bs[128 * 64];

  // Staging: 4 calls of (32 rows x 8 chunks of 16B). LDS dest is linear
  // (global_load_lds requires it); swizzle applied on the GLOBAL source side:
  // physical chunk p at row r holds logical chunk p ^ (r & 7).
  const int prow = tid >> 3;
  const int pchk = tid & 7;
  size_t asrc[4], bsrc[4];
  const unsigned short* wb = wbf + ((size_t)e << 20);
#pragma unroll
  for (int s = 0; s < 4; ++s) {
    int row = s * 32 + prow;
    int m = t * 128 + row;
    int g = tok[(m < c) ? m : 0];          // pad rows replay token 0 (stores guarded)
    int l = pchk ^ (row & 7);
    asrc[s] = (size_t)g * DIM + (size_t)l * 8;
    bsrc[s] = (size_t)(n0 + row) * DIM + (size_t)l * 8;
  }

  f32x4 acc[4][4] = {};
  const int wr = wave >> 1, wc = wave & 1;

  // LDS read offsets (elements). A-frag: lane holds A[row = lane&15][k = (lane>>4)*8 + j].
  int aoff[2][4], boff[2][4];
#pragma unroll
  for (int h = 0; h < 2; ++h)
#pragma unroll
    for (int m = 0; m < 4; ++m) {
      int row = wr * 64 + m * 16 + (lane & 15);
      int p = (h * 4 + (lane >> 4)) ^ (row & 7);
      aoff[h][m] = row * 64 + p * 8;
      int rowb = wc * 64 + m * 16 + (lane & 15);
      int pb = (h * 4 + (lane >> 4)) ^ (rowb & 7);
      boff[h][m] = rowb * 64 + pb * 8;
    }

  for (int k0 = 0; k0 < DIM; k0 += 64) {
#pragma unroll
    for (int s = 0; s < 4; ++s) {
      __builtin_amdgcn_global_load_lds(
          (const __attribute__((address_space(1))) unsigned int*)(xbf + asrc[s] + k0),
          (__attribute__((address_space(3))) unsigned int*)(&As[s * 2048 + wave * 512]),
          16, 0, 0);
      __builtin_amdgcn_global_load_lds(
          (const __attribute__((address_space(1))) unsigned int*)(wb + bsrc[s] + k0),
          (__attribute__((address_space(3))) unsigned int*)(&Bs[s * 2048 + wave * 512]),
          16, 0, 0);
    }
    __syncthreads();
#pragma unroll
    for (int h = 0; h < 2; ++h) {
      bf16x8 af[4], bfr[4];
#pragma unroll
      for (int m = 0; m < 4; ++m) af[m] = *(const bf16x8*)&As[aoff[h][m]];
#pragma unroll
      for (int n = 0; n < 4; ++n) bfr[n] = *(const bf16x8*)&Bs[boff[h][n]];
#pragma unroll
      for (int m = 0; m < 4; ++m)
#pragma unroll
        for (int n = 0; n < 4; ++n)
          acc[m][n] = __builtin_amdgcn_mfma_f32_16x16x32_bf16(af[m], bfr[n], acc[m][n], 0, 0, 0);
    }
    __syncthreads();
  }

  // Epilogue: C/D layout col = lane&15, row = (lane>>4)*4 + reg. Add bias, scatter to out[token].
  const int colb = n0 + wc * 64 + (lane & 15);
  float bias[4];
#pragma unroll
  for (int n = 0; n < 4; ++n) bias[n] = eb[(e << 10) + colb + n * 16];
#pragma unroll
  for (int m = 0; m < 4; ++m) {
    int rbase = t * 128 + wr * 64 + m * 16 + ((lane >> 4) << 2);
#pragma unroll
    for (int r = 0; r < 4; ++r) {
      int mm = rbase + r;
      if (mm < c) {
        int g = tok[mm];
        float* op = out + ((size_t)g << 10);
#pragma unroll
        for (int n = 0; n < 4; ++n) op[colb + n * 16] = acc[m][n][r] + bias[n];
      }
    }
  }
}

extern "C" void kernel_launch(void* const* d_in, const int* in_sizes, int n_in,
                              void* d_out, int out_size, void* d_ws, size_t ws_size,
                              hipStream_t stream) {
  const float* x  = (const float*)d_in[0];
  const float* rw = (const float*)d_in[1];
  const float* rb = (const float*)d_in[2];
  const float* ew = (const float*)d_in[3];
  const float* eb = (const float*)d_in[4];
  float* out = (float*)d_out;

  char* ws = (char*)d_ws;
  unsigned short* wbf = (unsigned short*)ws;                         // 16 MB
  unsigned short* xbf = (unsigned short*)(ws + (16u << 20));         // 32 MB
  int* tok    = (int*)(ws + (48u << 20));                            // 512 KB
  int* counts = (int*)(ws + (48u << 20) + (1u << 19));               // 32 B
  int* top    = (int*)(ws + (48u << 20) + (1u << 19) + 128);         // 64 KB

  k_convw<<<4096, 256, 0, stream>>>(ew, wbf);                        // 8M elems / 8 per thread
  k_router<<<NTOK / 16, 256, 0, stream>>>(x, rw, rb, xbf, top);      // 1024 blocks, 16 tok/block
  k_sort<<<1, 1024, 0, stream>>>(top, counts, tok);
  k_gemm<<<dim3(NEXP * 128, DIM / 128), 256, 0, stream>>>(xbf, wbf, eb, counts, tok, out);
}

// Round 7
// 126.779 us; speedup vs baseline: 2.3093x; 1.0587x over previous
//
#include <hip/hip_runtime.h>
#include <hip/hip_bf16.h>

// MoE top-1: N=16384 tokens, D=1024, E=8 experts.
// out[n] = expert_w[argmax(router(x[n]))] @ x[n] + expert_b[e]
//
// Pipeline: k_front (convw blocks + router blocks, merged launch) ->
// single-block counting sort -> grouped bf16-MFMA GEMM (double-buffered LDS,
// counted vmcnt, raw s_barrier, expert->XCD swizzle).

#define NTOK 16384
#define DIM  1024
#define NEXP 8

typedef __bf16 bf16x8 __attribute__((ext_vector_type(8)));
typedef float  f32x4  __attribute__((ext_vector_type(4)));

__device__ __forceinline__ unsigned short f2bf(float f) {
  unsigned int u = __builtin_bit_cast(unsigned int, f);
  u += 0x7FFFu + ((u >> 16) & 1u);   // round-to-nearest-even (finite inputs)
  return (unsigned short)(u >> 16);
}

// Merged front-end. Blocks [0,4096): expert_w f32->bf16 (8 elems/thread).
// Blocks [4096,5120): router — rw staged in LDS, one token per wave (4/wave via
// t-loop), lane-unique x slices (x read ONCE), f64-exact logits, shuffle
// reduce + argmax, fused x->bf16, writes top[n]. No atomics anywhere.
__global__ __launch_bounds__(256) void k_front(const float* __restrict__ x,
                                               const float* __restrict__ rw,
                                               const float* __restrict__ rb,
                                               const float* __restrict__ ew,
                                               unsigned short* __restrict__ xbf,
                                               unsigned short* __restrict__ wbf,
                                               int* __restrict__ top) {
  __shared__ float wlds[NEXP * DIM];   // 32 KB (router blocks only)
  const int tid = threadIdx.x;

  if (blockIdx.x < 4096) {             // ---- convw part ----
    size_t i = ((size_t)blockIdx.x * 256 + tid) * 8;
    const float4* p = (const float4*)(ew + i);
    float4 a = p[0], b = p[1];
    unsigned int w0 = (unsigned)f2bf(a.x) | ((unsigned)f2bf(a.y) << 16);
    unsigned int w1 = (unsigned)f2bf(a.z) | ((unsigned)f2bf(a.w) << 16);
    unsigned int w2 = (unsigned)f2bf(b.x) | ((unsigned)f2bf(b.y) << 16);
    unsigned int w3 = (unsigned)f2bf(b.z) | ((unsigned)f2bf(b.w) << 16);
    *(uint4*)(wbf + i) = make_uint4(w0, w1, w2, w3);
    return;
  }

  // ---- router part ----
  const int rbid = blockIdx.x - 4096;
  const int lane = tid & 63;
  const int wave = tid >> 6;
#pragma unroll
  for (int i = 0; i < 8; ++i)
    ((float4*)wlds)[tid + 256 * i] = ((const float4*)rw)[tid + 256 * i];
  __syncthreads();

  const int ea = lane & 7;
#pragma unroll 1
  for (int t = 0; t < 4; ++t) {
    const int n = (rbid << 4) + (wave << 2) + t;
    const float4* xp = (const float4*)(x + ((size_t)n << 10)) + lane;
    float4 xv[4];
#pragma unroll
    for (int j = 0; j < 4; ++j) xv[j] = xp[j * 64];   // coalesced, lane-unique

    // fused bf16 conversion + store (8 B/lane/chunk, coalesced)
#pragma unroll
    for (int j = 0; j < 4; ++j) {
      unsigned int c0 = (unsigned)f2bf(xv[j].x) | ((unsigned)f2bf(xv[j].y) << 16);
      unsigned int c1 = (unsigned)f2bf(xv[j].z) | ((unsigned)f2bf(xv[j].w) << 16);
      *(uint2*)(xbf + ((size_t)n << 10) + j * 256 + lane * 4) = make_uint2(c0, c1);
    }

    double p[8] = {};
#pragma unroll
    for (int e = 0; e < 8; ++e)
#pragma unroll
      for (int j = 0; j < 4; ++j) {
        float4 wv = *(const float4*)&wlds[e * 1024 + j * 256 + lane * 4];
        p[e] += (double)xv[j].x * (double)wv.x;
        p[e] += (double)xv[j].y * (double)wv.y;
        p[e] += (double)xv[j].z * (double)wv.z;
        p[e] += (double)xv[j].w * (double)wv.w;
      }

    // subgroup (8-lane) sums of all 8 partials
#pragma unroll
    for (int e = 0; e < 8; ++e) {
      p[e] += __shfl_xor(p[e], 1);
      p[e] += __shfl_xor(p[e], 2);
      p[e] += __shfl_xor(p[e], 4);
    }
    // static select tree: s = p[ea] without runtime indexing (rule #20)
    double q0 = (ea & 1) ? p[1] : p[0];
    double q1 = (ea & 1) ? p[3] : p[2];
    double q2 = (ea & 1) ? p[5] : p[4];
    double q3 = (ea & 1) ? p[7] : p[6];
    double r0 = (ea & 2) ? q1 : q0;
    double r1 = (ea & 2) ? q3 : q2;
    double s  = (ea & 4) ? r1 : r0;
    // sum across the 8 subgroups
    s += __shfl_xor(s, 8);
    s += __shfl_xor(s, 16);
    s += __shfl_xor(s, 32);
    s += (double)rb[ea];
    // argmax over experts (lane bits 0-2); first index on ties (np.argmax)
    double bv = s;
    int bi = ea;
#pragma unroll
    for (int mask = 1; mask <= 4; mask <<= 1) {
      double ov = __shfl_xor(bv, mask);
      int oi = __shfl_xor(bi, mask);
      if (ov > bv || (ov == bv && oi < bi)) { bv = ov; bi = oi; }
    }
    if (lane == 0) top[n] = bi;
  }
}

// Counting sort of 16384 expert ids in ONE block (1024 threads x 16 tokens).
// Per-thread histogram packed as 2x u64 (8 experts x 16-bit fields); Hillis-
// Steele scan over packed u64s in LDS; ordered scatter into per-expert lists.
// Deterministic; lists sorted by token index (GEMM gather locality).
__global__ __launch_bounds__(1024) void k_sort(const int* __restrict__ top,
                                               int* __restrict__ counts,
                                               int* __restrict__ tok) {
  __shared__ unsigned long long sc[2][2][1024];  // 32 KB
  const int t = threadIdx.x;

  int4 v[4];
  const int4* tp = (const int4*)(top + t * 16);
#pragma unroll
  for (int i = 0; i < 4; ++i) v[i] = tp[i];

  unsigned long long h0 = 0, h1 = 0;
#pragma unroll
  for (int i = 0; i < 16; ++i) {
    int e = ((const int*)v)[i];
    if (e < 4) h0 += 1ull << (16 * e);
    else       h1 += 1ull << (16 * (e - 4));
  }
  sc[0][0][t] = h0;
  sc[0][1][t] = h1;
  __syncthreads();

  int cur = 0;
  for (int s = 1; s < 1024; s <<= 1) {
    unsigned long long a0 = sc[cur][0][t], a1 = sc[cur][1][t];
    if (t >= s) { a0 += sc[cur][0][t - s]; a1 += sc[cur][1][t - s]; }
    sc[cur ^ 1][0][t] = a0;
    sc[cur ^ 1][1][t] = a1;
    cur ^= 1;
    __syncthreads();
  }

  unsigned long long b0 = sc[cur][0][t] - h0;
  unsigned long long b1 = sc[cur][1][t] - h1;
  if (t == 1023) {
    unsigned long long i0 = sc[cur][0][t], i1 = sc[cur][1][t];
#pragma unroll
    for (int e = 0; e < 4; ++e) counts[e] = (int)((i0 >> (16 * e)) & 0xFFFF);
#pragma unroll
    for (int e = 0; e < 4; ++e) counts[4 + e] = (int)((i1 >> (16 * e)) & 0xFFFF);
  }
#pragma unroll
  for (int i = 0; i < 16; ++i) {
    int e = ((const int*)v)[i];
    int pos;
    if (e < 4) {
      pos = (int)((b0 >> (16 * e)) & 0xFFFF);
      b0 += 1ull << (16 * e);
    } else {
      int f = e - 4;
      pos = (int)((b1 >> (16 * f)) & 0xFFFF);
      b1 += 1ull << (16 * f);
    }
    tok[(e << 14) + pos] = t * 16 + i;
  }
}

// Grouped GEMM: C[m,o] = sum_d Xg[m,d] * W[o,d]. 128x128 tile, BK=64, 4 waves,
// mfma_f32_16x16x32_bf16. Double-buffered LDS staging with counted vmcnt and
// raw s_barrier (no vmcnt(0) drain in the main loop — T3+T4 pattern).
// 1D grid 8192, swizzled: xcd = bid&7 = expert; within an XCD, col-tile varies
// fastest so W_e (2 MB) and the current X token-tile stay L2-resident.
__global__ __launch_bounds__(256, 2) void k_gemm(const unsigned short* __restrict__ xbf,
                                                 const unsigned short* __restrict__ wbf,
                                                 const float* __restrict__ eb,
                                                 const int* __restrict__ counts,
                                                 const int* __restrict__ tokall,
                                                 float* __restrict__ out) {
  const int bid = blockIdx.x;          // 0..8191
  const int e = bid & 7;               // expert == XCD (dispatch round-robins %8)
  const int loc = bid >> 3;            // 0..1023 within XCD
  const int cb = loc & 7;              // col tile (fastest -> temporal locality)
  const int t = loc >> 3;              // token tile 0..127
  const int c = counts[e];
  if (t * 128 >= c) return;
  const int n0 = cb << 7;
  const int* tok = tokall + (e << 14);
  const int tid = threadIdx.x;
  const int lane = tid & 63;
  const int wave = tid >> 6;

  __shared__ unsigned short As[2][128 * 64];  // 2 x 16 KB, chunk-swizzled
  __shared__ unsigned short Bs[2][128 * 64];

  // Staging addresses: 4 x (32 rows x 8 chunks of 16B) per buffer. LDS dest is
  // linear (global_load_lds requirement); swizzle on the GLOBAL source side:
  // physical chunk p at row r holds logical chunk p ^ (r & 7).
  const int prow = tid >> 3;
  const int pchk = tid & 7;
  size_t asrc[4], bsrc[4];
  const unsigned short* wb = wbf + ((size_t)e << 20);
#pragma unroll
  for (int s = 0; s < 4; ++s) {
    int row = s * 32 + prow;
    int m = t * 128 + row;
    int g = tok[(m < c) ? m : 0];          // pad rows replay token 0 (stores guarded)
    int l = pchk ^ (row & 7);
    asrc[s] = (size_t)g * DIM + (size_t)l * 8;
    bsrc[s] = (size_t)(n0 + row) * DIM + (size_t)l * 8;
  }

  f32x4 acc[4][4] = {};
  const int wr = wave >> 1, wc = wave & 1;

  // LDS read offsets (elements). A-frag: lane holds A[row = lane&15][k = (lane>>4)*8 + j].
  int aoff[2][4], boff[2][4];
#pragma unroll
  for (int h = 0; h < 2; ++h)
#pragma unroll
    for (int m = 0; m < 4; ++m) {
      int row = wr * 64 + m * 16 + (lane & 15);
      int p = (h * 4 + (lane >> 4)) ^ (row & 7);
      aoff[h][m] = row * 64 + p * 8;
      int rowb = wc * 64 + m * 16 + (lane & 15);
      int pb = (h * 4 + (lane >> 4)) ^ (rowb & 7);
      boff[h][m] = rowb * 64 + pb * 8;
    }

  // stage one K-tile (8 global_load_lds of 16B per thread) into buffer b
  auto stage = [&](int b, int k0) {
#pragma unroll
    for (int s = 0; s < 4; ++s) {
      __builtin_amdgcn_global_load_lds(
          (const __attribute__((address_space(1))) unsigned int*)(xbf + asrc[s] + k0),
          (__attribute__((address_space(3))) unsigned int*)(&As[b][s * 2048 + wave * 512]),
          16, 0, 0);
      __builtin_amdgcn_global_load_lds(
          (const __attribute__((address_space(1))) unsigned int*)(wb + bsrc[s] + k0),
          (__attribute__((address_space(3))) unsigned int*)(&Bs[b][s * 2048 + wave * 512]),
          16, 0, 0);
    }
  };

  stage(0, 0);                          // 8 loads in flight
  for (int k = 0; k < 16; ++k) {
    if (k < 15) {
      stage((k + 1) & 1, (k + 1) * 64); // 16 in flight
      asm volatile("s_waitcnt vmcnt(8)" ::: "memory");  // current tile landed
    } else {
      asm volatile("s_waitcnt vmcnt(0)" ::: "memory");
    }
    __builtin_amdgcn_s_barrier();       // raw barrier: no compiler vmcnt(0) drain
    __builtin_amdgcn_sched_barrier(0);
    const unsigned short* Ab = As[k & 1];
    const unsigned short* Bb = Bs[k & 1];
#pragma unroll
    for (int h = 0; h < 2; ++h) {
      bf16x8 af[4], bfr[4];
#pragma unroll
      for (int m = 0; m < 4; ++m) af[m] = *(const bf16x8*)&Ab[aoff[h][m]];
#pragma unroll
      for (int n = 0; n < 4; ++n) bfr[n] = *(const bf16x8*)&Bb[boff[h][n]];
#pragma unroll
      for (int m = 0; m < 4; ++m)
#pragma unroll
        for (int n = 0; n < 4; ++n)
          acc[m][n] = __builtin_amdgcn_mfma_f32_16x16x32_bf16(af[m], bfr[n], acc[m][n], 0, 0, 0);
    }
    __builtin_amdgcn_s_barrier();       // all waves done reading before re-stage
  }

  // Epilogue: C/D layout col = lane&15, row = (lane>>4)*4 + reg. Bias + scatter.
  const int colb = n0 + wc * 64 + (lane & 15);
  float bias[4];
#pragma unroll
  for (int n = 0; n < 4; ++n) bias[n] = eb[(e << 10) + colb + n * 16];
#pragma unroll
  for (int m = 0; m < 4; ++m) {
    int rbase = t * 128 + wr * 64 + m * 16 + ((lane >> 4) << 2);
#pragma unroll
    for (int r = 0; r < 4; ++r) {
      int mm = rbase + r;
      if (mm < c) {
        int g = tok[mm];
        float* op = out + ((size_t)g << 10);
#pragma unroll
        for (int n = 0; n < 4; ++n) op[colb + n * 16] = acc[m][n][r] + bias[n];
      }
    }
  }
}

extern "C" void kernel_launch(void* const* d_in, const int* in_sizes, int n_in,
                              void* d_out, int out_size, void* d_ws, size_t ws_size,
                              hipStream_t stream) {
  const float* x  = (const float*)d_in[0];
  const float* rw = (const float*)d_in[1];
  const float* rb = (const float*)d_in[2];
  const float* ew = (const float*)d_in[3];
  const float* eb = (const float*)d_in[4];
  float* out = (float*)d_out;

  char* ws = (char*)d_ws;
  unsigned short* wbf = (unsigned short*)ws;                         // 16 MB
  unsigned short* xbf = (unsigned short*)(ws + (16u << 20));         // 32 MB
  int* tok    = (int*)(ws + (48u << 20));                            // 512 KB
  int* counts = (int*)(ws + (48u << 20) + (1u << 19));               // 32 B
  int* top    = (int*)(ws + (48u << 20) + (1u << 19) + 128);         // 64 KB

  k_front<<<4096 + NTOK / 16, 256, 0, stream>>>(x, rw, rb, ew, xbf, wbf, top);
  k_sort<<<1, 1024, 0, stream>>>(top, counts, tok);
  k_gemm<<<8192, 256, 0, stream>>>(xbf, wbf, eb, counts, tok, out);
}